// Round 4
// baseline (360.197 us; speedup 1.0000x reference)
//
#include <hip/hip_runtime.h>

// Problem constants (from reference setup_inputs)
#define S 4096
#define B 32
#define H 512

// Native Clang vector type: accepted by __builtin_nontemporal_load
// (HIP's float4 is a class and is rejected). Same 16-B layout.
typedef float nfloat4 __attribute__((ext_vector_type(4)));

// ---------------------------------------------------------------------------
// Kernel 1: v[b,h] = sum_g hidden[b,g] * W[g,h]   (v = hidden @ W, [B,H])
// grid (B, 2), 256 threads; thread owns one output column h; W reads coalesced.
// bias term hidden[b]·attn_b is a per-b constant -> cancels in softmax, skipped.
// ~3 us, not a bottleneck.
// ---------------------------------------------------------------------------
__global__ __launch_bounds__(256) void proj_kernel(
    const float* __restrict__ hidden,
    const float* __restrict__ W,
    float* __restrict__ v)
{
    __shared__ float sh[H];
    const int b = blockIdx.x;
    const int h = blockIdx.y * 256 + threadIdx.x;
    for (int g = threadIdx.x; g < H; g += 256)
        sh[g] = hidden[b * H + g];
    __syncthreads();

    float acc = 0.f;
#pragma unroll 16
    for (int g = 0; g < H; ++g)
        acc += sh[g] * W[g * H + h];
    v[b * H + h] = acc;
}

// ---------------------------------------------------------------------------
// Kernel 2: scoresT[b*S + s] = enc[s,b,:] . v[b,:]
// One wave per FOUR s-rows of the SAME b: v fragment loaded once per wave
// (4x amortized), four independent FMA/reduction chains (MLP + DS-pipe ILP),
// single coalesced float4 store of (s0..s0+3) results from lane 0.
// enc loads nontemporal: pure stream, keep L2 for v.
// q = wave id in [0, S*B/4): b = q & 31, s0 = (q >> 5)*4.
// ---------------------------------------------------------------------------
__global__ __launch_bounds__(256) void score_kernel(
    const nfloat4* __restrict__ enc4,
    const nfloat4* __restrict__ v4,
    float* __restrict__ scoresT)
{
    const int wave = threadIdx.x >> 6;
    const int lane = threadIdx.x & 63;
    const int q = blockIdx.x * 4 + wave;
    const int b = q & (B - 1);
    const int s0 = (q >> 5) << 2;

    const size_t rowStride = B * (H / 4);          // float4s per s step
    const nfloat4* e0 = enc4 + (size_t)(s0 * B + b) * (H / 4);
    const nfloat4* e1 = e0 + rowStride;
    const nfloat4* e2 = e1 + rowStride;
    const nfloat4* e3 = e2 + rowStride;
    const nfloat4* w  = v4 + (size_t)b * (H / 4);

    nfloat4 wa = w[lane];
    nfloat4 wb = w[64 + lane];

    nfloat4 a0 = __builtin_nontemporal_load(&e0[lane]);
    nfloat4 b0 = __builtin_nontemporal_load(&e0[64 + lane]);
    nfloat4 a1 = __builtin_nontemporal_load(&e1[lane]);
    nfloat4 b1 = __builtin_nontemporal_load(&e1[64 + lane]);
    nfloat4 a2 = __builtin_nontemporal_load(&e2[lane]);
    nfloat4 b2 = __builtin_nontemporal_load(&e2[64 + lane]);
    nfloat4 a3 = __builtin_nontemporal_load(&e3[lane]);
    nfloat4 b3 = __builtin_nontemporal_load(&e3[64 + lane]);

    float d0 = a0.x * wa.x + a0.y * wa.y + a0.z * wa.z + a0.w * wa.w
             + b0.x * wb.x + b0.y * wb.y + b0.z * wb.z + b0.w * wb.w;
    float d1 = a1.x * wa.x + a1.y * wa.y + a1.z * wa.z + a1.w * wa.w
             + b1.x * wb.x + b1.y * wb.y + b1.z * wb.z + b1.w * wb.w;
    float d2 = a2.x * wa.x + a2.y * wa.y + a2.z * wa.z + a2.w * wa.w
             + b2.x * wb.x + b2.y * wb.y + b2.z * wb.z + b2.w * wb.w;
    float d3 = a3.x * wa.x + a3.y * wa.y + a3.z * wa.z + a3.w * wa.w
             + b3.x * wb.x + b3.y * wb.y + b3.z * wb.z + b3.w * wb.w;

#pragma unroll
    for (int off = 32; off >= 1; off >>= 1) {
        d0 += __shfl_down(d0, off, 64);
        d1 += __shfl_down(d1, off, 64);
        d2 += __shfl_down(d2, off, 64);
        d3 += __shfl_down(d3, off, 64);
    }

    if (lane == 0) {
        float4 st;
        st.x = d0; st.y = d1; st.z = d2; st.w = d3;
        *(float4*)&scoresT[(size_t)b * S + s0] = st;
    }
}

// ---------------------------------------------------------------------------
// Kernel 3: out[b, :] = softmax(scoresT[b, :]) over S.
// 32 blocks x 1024 threads; exactly one float4 per thread (4096 = 1024*4).
// Two reduction trees (max, sum) via wave shuffle + 16-slot LDS.
// ---------------------------------------------------------------------------
__global__ __launch_bounds__(1024) void softmax_kernel(
    const float4* __restrict__ scoresT4,
    float4* __restrict__ out4)
{
    __shared__ float red[16];

    const int b = blockIdx.x;
    const int t = threadIdx.x;
    const int lane = t & 63;
    const int wv = t >> 6;

    float4 x = scoresT4[(size_t)b * (S / 4) + t];

    float m = fmaxf(fmaxf(x.x, x.y), fmaxf(x.z, x.w));
#pragma unroll
    for (int off = 32; off >= 1; off >>= 1)
        m = fmaxf(m, __shfl_down(m, off, 64));
    if (lane == 0) red[wv] = m;
    __syncthreads();
#pragma unroll
    for (int i = 0; i < 16; ++i)
        m = fmaxf(m, red[i]);

    float4 ex;
    ex.x = __expf(x.x - m);
    ex.y = __expf(x.y - m);
    ex.z = __expf(x.z - m);
    ex.w = __expf(x.w - m);
    float ssum = ex.x + ex.y + ex.z + ex.w;
#pragma unroll
    for (int off = 32; off >= 1; off >>= 1)
        ssum += __shfl_down(ssum, off, 64);
    __syncthreads();                 // everyone done reading red (max phase)
    if (lane == 0) red[wv] = ssum;
    __syncthreads();

    float tot = 0.f;
#pragma unroll
    for (int i = 0; i < 16; ++i)
        tot += red[i];

    const float inv = 1.f / tot;
    ex.x *= inv; ex.y *= inv; ex.z *= inv; ex.w *= inv;
    out4[(size_t)b * (S / 4) + t] = ex;
}

// ---------------------------------------------------------------------------
extern "C" void kernel_launch(void* const* d_in, const int* in_sizes, int n_in,
                              void* d_out, int out_size, void* d_ws, size_t ws_size,
                              hipStream_t stream)
{
    const float* hidden = (const float*)d_in[0];   // [B, H]
    const float* enc    = (const float*)d_in[1];   // [S, B, H]
    const float* W      = (const float*)d_in[2];   // [H, H]  (g, h)
    // d_in[3] = attn_b: per-b constant under softmax -> unused.

    float* out     = (float*)d_out;                // [B, 1, S] -> B*S floats
    float* v       = (float*)d_ws;                 // [B, H]   (64 KB)
    float* scoresT = v + B * H;                    // [B, S]   (512 KB)

    proj_kernel<<<dim3(B, 2), 256, 0, stream>>>(hidden, W, v);
    score_kernel<<<(S * B / 4) / 4, 256, 0, stream>>>(
        (const nfloat4*)enc, (const nfloat4*)v, scoresT);
    softmax_kernel<<<B, 1024, 0, stream>>>(
        (const float4*)scoresT, (float4*)out);
}